// Round 11
// baseline (76.707 us; speedup 1.0000x reference)
//
#include <hip/hip_runtime.h>
#include <hip/hip_bf16.h>

typedef short short8 __attribute__((ext_vector_type(8)));
typedef float floatx4 __attribute__((ext_vector_type(4)));
typedef float floatx16 __attribute__((ext_vector_type(16)));

#define HID 32
#define NTD 8
#define FAN_IN 18

// round-to-nearest-even f32 -> bf16 (bit pattern in a short)
__device__ __forceinline__ short f2bf(float f) {
    union { float f; unsigned u; } v; v.f = f;
    unsigned r = v.u + 0x7fffu + ((v.u >> 16) & 1u);
    return (short)(r >> 16);
}

// f32 -> bf16 with LSB stolen: RNE at bit 17, LSB carries one mask bit
__device__ __forceinline__ unsigned short pack_emb(float f, unsigned bit) {
    union { float f; unsigned u; } v; v.f = f;
    unsigned r = v.u + 0xFFFFu + ((v.u >> 17) & 1u);
    unsigned short s = (unsigned short)((r >> 16) & 0xFFFEu);
    return (unsigned short)(s | bit);
}

// sigmoid via hw exp2 + hw rcp
__device__ __forceinline__ float fast_sigmoid(float x) {
    float e = __builtin_amdgcn_exp2f(x * -1.44269504f);
    return __builtin_amdgcn_rcpf(1.0f + e);
}

// ---------------- build kernel ----------------
// T[n] = 16B row: 8 bf16 emb, LSBs carry the 8-bit quantized mask.
// aux (at T + N*16): per-lane precomputed MFMA A-fragments + W2 permutation:
//   aux[lane] (96B): as(16B) | ad(16B) | w2r[16] (64B);  bias2 at aux + 6144.
__global__ void build_table(const float* __restrict__ emb,
                            const float* __restrict__ mask,
                            const float* __restrict__ W1,
                            const float* __restrict__ b1,
                            const float* __restrict__ W2,
                            const float* __restrict__ b2,
                            unsigned short* __restrict__ T, int N) {
    int n = blockIdx.x * blockDim.x + threadIdx.x;

    // --- aux build (block 0, threads 0..63) ---
    if (blockIdx.x == 0 && threadIdx.x < 64) {
        int t = threadIdx.x;
        int c = t & 31;
        int h = t >> 5;
        // A_s: h=0: k=j -> W1 rows 0-7 (emb_s);  h=1: j0: W1 row 16 (ms), j1: b1
        // A_d: h=0: j0: W1 row 17 (md);          h=1: k=8+j -> W1 rows 8-15 (emb_d)
        short8 as, ad;
        #pragma unroll
        for (int j = 0; j < 8; ++j) {
            float vs = 0.f, vd = 0.f;
            if (h == 0) {
                vs = W1[j * HID + c];
                if (j == 0) vd = W1[17 * HID + c];
            } else {
                if (j == 0) vs = W1[16 * HID + c];
                else if (j == 1) vs = b1[c];
                vd = W1[(8 + j) * HID + c];
            }
            as[j] = f2bf(vs);
            ad[j] = f2bf(vd);
        }
        char* aux = (char*)(T + (size_t)N * 8) + (size_t)t * 96;
        *(short8*)(aux) = as;
        *(short8*)(aux + 16) = ad;
        float w2r[16];
        #pragma unroll
        for (int q = 0; q < 16; ++q)
            w2r[q] = W2[(q & 3) + 8 * (q >> 2) + 4 * h];
        *(float4*)(aux + 32) = *(float4*)(&w2r[0]);
        *(float4*)(aux + 48) = *(float4*)(&w2r[4]);
        *(float4*)(aux + 64) = *(float4*)(&w2r[8]);
        *(float4*)(aux + 80) = *(float4*)(&w2r[12]);
        if (t == 0)
            *(float*)((char*)(T + (size_t)N * 8) + 6144) = b2[0];
    }

    if (n >= N) return;
    const float4* p = (const float4*)(emb + (size_t)n * NTD);
    float4 lo = p[0], hi = p[1];
    float ev[8] = {lo.x, lo.y, lo.z, lo.w, hi.x, hi.y, hi.z, hi.w};
    float mf = mask[n] * 255.0f + 0.5f;
    unsigned m8 = (unsigned)mf; if (m8 > 255u) m8 = 255u;
    unsigned short row[8];
    #pragma unroll
    for (int j = 0; j < 8; ++j)
        row[j] = pack_emb(ev[j], (m8 >> j) & 1u);
    int4 o;
    o.x = (int)((unsigned)row[0] | ((unsigned)row[1] << 16));
    o.y = (int)((unsigned)row[2] | ((unsigned)row[3] << 16));
    o.z = (int)((unsigned)row[4] | ((unsigned)row[5] << 16));
    o.w = (int)((unsigned)row[6] | ((unsigned)row[7] << 16));
    *(int4*)(T + (size_t)n * 8) = o;
}

// decode the 8-bit mask from the 8 LSBs of a row
__device__ __forceinline__ unsigned decode_m8(int4 r) {
    unsigned m;
    m  = ((unsigned)r.x & 1u);
    m |= (((unsigned)r.x >> 16) & 1u) << 1;
    m |= ((unsigned)r.y & 1u) << 2;
    m |= (((unsigned)r.y >> 16) & 1u) << 3;
    m |= ((unsigned)r.z & 1u) << 4;
    m |= (((unsigned)r.z >> 16) & 1u) << 5;
    m |= ((unsigned)r.w & 1u) << 6;
    m |= (((unsigned)r.w >> 16) & 1u) << 7;
    return m;
}

// build B-fragments for one 32-edge tile from this lane's row
__device__ __forceinline__ void tile_frags(int4 row, int h, short8& fb1, short8& fb2) {
    unsigned m8 = decode_m8(row);
    unsigned m8p = (unsigned)__shfl_xor((int)m8, 32, 64);   // partner's mask bits
    float mfv = (float)m8p * (1.0f / 255.0f);
    unsigned mbf = (unsigned)(unsigned short)f2bf(mfv);
    int4 b1i, b2i;
    if (h) {
        b1i.x = (int)(mbf | 0x3F800000u);  // low short = ms (k8), high short = 1.0 (k9)
        b1i.y = 0; b1i.z = 0; b1i.w = 0;
        b2i = row;                          // k8-15 = emb_d
    } else {
        b1i = row;                          // k0-7 = emb_s
        b2i.x = (int)mbf;                   // low short = md (k0)
        b2i.y = 0; b2i.z = 0; b2i.w = 0;
    }
    fb1 = __builtin_bit_cast(short8, b1i);
    fb2 = __builtin_bit_cast(short8, b2i);
}

// ---------------- main kernel: ONE 64-edge group per wave (HW churn hides latency)
// Lane c (<32) owns the 16B s-row of edge c; lane 32+c owns the 16B d-row of edge c.
// MFMA1 (A_s): k0-7 = W1 rows 0-7 (emb_s), k8 = W1 row 16 (mask_s), k9 = b1.
// MFMA2 (A_d): k0 = W1 row 17 (mask_d), k8-15 = W1 rows 8-15 (emb_d).

template <int ESZ>
__device__ __forceinline__ void do_group(const char* __restrict__ ei,
                                         const char* __restrict__ Tc,
                                         size_t auxOff,
                                         float* __restrict__ out, unsigned E,
                                         unsigned grp, int h, int c, int lane) {
    const char* idxBase = ei + (h ? (size_t)E * ESZ : 0);
    const unsigned cc = (unsigned)c;

    // indices for this wave's 64 edges (this lane: edges grp*64+c and grp*64+32+c)
    unsigned eA = grp * 64u + cc;
    unsigned eB = eA + 32u;
    if (eA >= E) eA = E - 1u;
    if (eB >= E) eB = E - 1u;
    unsigned iA = *(const unsigned*)(idxBase + (size_t)eA * ESZ);
    unsigned iB = *(const unsigned*)(idxBase + (size_t)eB * ESZ);

    // precomputed per-lane constants (L1/L2-resident aux table)
    const char* aux = Tc + auxOff + (size_t)lane * 96u;
    short8 as = *(const short8*)(aux);
    short8 ad = *(const short8*)(aux + 16);
    float4 w0 = *(const float4*)(aux + 32);
    float4 w1v = *(const float4*)(aux + 48);
    float4 w2v = *(const float4*)(aux + 64);
    float4 w3v = *(const float4*)(aux + 80);
    const float bias2 = *(const float*)(Tc + auxOff + 6144);

    // row gathers (one dwordx4 per node reference)
    int4 rA = *(const int4*)(Tc + (size_t)iA * 16u);
    int4 rB = *(const int4*)(Tc + (size_t)iB * 16u);

    // fragments
    short8 fb1A, fb2A, fb1B, fb2B;
    tile_frags(rA, h, fb1A, fb2A);
    tile_frags(rB, h, fb1B, fb2B);

    // layer 1: two 32-edge tiles, 2 MFMAs each
    floatx16 accA = {0.f,0.f,0.f,0.f,0.f,0.f,0.f,0.f,0.f,0.f,0.f,0.f,0.f,0.f,0.f,0.f};
    floatx16 accB = accA;
    accA = __builtin_amdgcn_mfma_f32_32x32x16_bf16(as, fb1A, accA, 0, 0, 0);
    accB = __builtin_amdgcn_mfma_f32_32x32x16_bf16(as, fb1B, accB, 0, 0, 0);
    accA = __builtin_amdgcn_mfma_f32_32x32x16_bf16(ad, fb2A, accA, 0, 0, 0);
    accB = __builtin_amdgcn_mfma_f32_32x32x16_bf16(ad, fb2B, accB, 0, 0, 0);

    // layer 2: lane(h,c) holds H rows (q&3)+8*(q>>2)+4h of its edge
    float w2r[16] = {w0.x, w0.y, w0.z, w0.w, w1v.x, w1v.y, w1v.z, w1v.w,
                     w2v.x, w2v.y, w2v.z, w2v.w, w3v.x, w3v.y, w3v.z, w3v.w};
    float pA0 = 0.f, pA1 = 0.f, pB0 = 0.f, pB1 = 0.f;
    #pragma unroll
    for (int q = 0; q < 16; q += 2) {
        pA0 += fmaxf(accA[q],     0.f) * w2r[q];
        pA1 += fmaxf(accA[q + 1], 0.f) * w2r[q + 1];
        pB0 += fmaxf(accB[q],     0.f) * w2r[q];
        pB1 += fmaxf(accB[q + 1], 0.f) * w2r[q + 1];
    }
    float pA = pA0 + pA1;
    float pB = pB0 + pB1;
    pA += __shfl_xor(pA, 32, 64);   // combine the two h-halves
    pB += __shfl_xor(pB, 32, 64);
    float vA = fast_sigmoid(pA + bias2);
    float vB = fast_sigmoid(pB + bias2);

    float v = (h == 0) ? vA : vB;
    unsigned e = (grp << 6) + (unsigned)lane;
    if (e < E) out[e] = v;
}

__global__ __launch_bounds__(256, 8) void lg_table_kernel(
    const char* __restrict__ ei_bytes,
    const unsigned short* __restrict__ T,
    float* __restrict__ out,
    long long E_, int N)
{
    const unsigned E = (unsigned)E_;
    const unsigned nGroups = (E + 63u) >> 6;
    const int lane = threadIdx.x & 63;
    const unsigned waveId = (unsigned)(blockIdx.x * (blockDim.x >> 6) + (threadIdx.x >> 6));
    if (waveId >= nGroups) return;

    // detect edge_index element size: int64 (odd 4B words all zero) vs int32
    const int* ei32 = (const int*)ei_bytes;
    int probe = ei32[2 * lane + 1];
    unsigned long long nz = __ballot(probe != 0);
    const int esz = (nz == 0ull) ? 8 : 4;

    const int c = lane & 31;
    const int h = lane >> 5;
    const size_t auxOff = (size_t)N * 16u;

    if (esz == 8)
        do_group<8>(ei_bytes, (const char*)T, auxOff, out, E, waveId, h, c, lane);
    else
        do_group<4>(ei_bytes, (const char*)T, auxOff, out, E, waveId, h, c, lane);
}

// ---------------- fallback (round-1 kernel, used if d_ws too small) ----------------
__global__ __launch_bounds__(256, 4) void lg_kernel(
    const float* __restrict__ nt_emb,
    const char* __restrict__ ei_bytes,
    const float* __restrict__ lm_mask,
    const float* __restrict__ W1,
    const float* __restrict__ b1,
    const float* __restrict__ W2,
    const float* __restrict__ b2,
    float* __restrict__ out,
    long long E)
{
    const int lane = threadIdx.x & 63;
    const int waveInBlock = threadIdx.x >> 6;
    const long long waveId = (long long)blockIdx.x * (blockDim.x >> 6) + waveInBlock;
    const long long nWaves = (long long)gridDim.x * (blockDim.x >> 6);

    const int* ei32 = (const int*)ei_bytes;
    int probe = ei32[2 * lane + 1];
    unsigned long long nz = __ballot(probe != 0);
    const long long esz = (nz == 0ull) ? 8 : 4;

    const int r = lane & 15;
    const int g = lane >> 4;

    short8 a0, a1;
    #pragma unroll
    for (int j = 0; j < 8; ++j) {
        int k = g * 8 + j;
        float v0 = 0.f, v1 = 0.f;
        if (k < FAN_IN)       { v0 = W1[k * HID + r];      v1 = W1[k * HID + 16 + r]; }
        else if (k == FAN_IN) { v0 = b1[r];                v1 = b1[16 + r]; }
        a0[j] = f2bf(v0);
        a1[j] = f2bf(v1);
    }

    float w2v0[4], w2v1[4];
    #pragma unroll
    for (int q = 0; q < 4; ++q) {
        w2v0[q] = W2[g * 4 + q];
        w2v1[q] = W2[16 + g * 4 + q];
    }
    const float bias2 = b2[0];

    const long long nGroups = (E + 15) >> 4;
    for (long long grp = waveId; grp < nGroups; grp += nWaves) {
        long long e = (grp << 4) + r;
        const bool valid = (e < E);
        long long ec = valid ? e : (E - 1);

        int s = *(const int*)(ei_bytes + ec * esz);
        int d = *(const int*)(ei_bytes + (E + ec) * esz);

        short8 fb;
        #pragma unroll
        for (int j = 0; j < 8; ++j) fb[j] = 0;
        if (g < 2) {
            const float4* p = (const float4*)(nt_emb + (long long)(g == 0 ? s : d) * NTD);
            float4 lo = p[0];
            float4 hi = p[1];
            fb[0] = f2bf(lo.x); fb[1] = f2bf(lo.y); fb[2] = f2bf(lo.z); fb[3] = f2bf(lo.w);
            fb[4] = f2bf(hi.x); fb[5] = f2bf(hi.y); fb[6] = f2bf(hi.z); fb[7] = f2bf(hi.w);
        } else if (g == 2) {
            fb[0] = f2bf(lm_mask[s]);
            fb[1] = f2bf(lm_mask[d]);
            fb[2] = (short)0x3F80;
        }

        floatx4 acc0 = {0.f, 0.f, 0.f, 0.f};
        floatx4 acc1 = {0.f, 0.f, 0.f, 0.f};
        acc0 = __builtin_amdgcn_mfma_f32_16x16x32_bf16(a0, fb, acc0, 0, 0, 0);
        acc1 = __builtin_amdgcn_mfma_f32_16x16x32_bf16(a1, fb, acc1, 0, 0, 0);

        float partial = 0.f;
        #pragma unroll
        for (int q = 0; q < 4; ++q) {
            partial += fmaxf(acc0[q], 0.f) * w2v0[q];
            partial += fmaxf(acc1[q], 0.f) * w2v1[q];
        }
        partial += __shfl_xor(partial, 16, 64);
        partial += __shfl_xor(partial, 32, 64);

        float val = fast_sigmoid(partial + bias2);
        if (g == 0 && valid) out[e] = val;
    }
}

extern "C" void kernel_launch(void* const* d_in, const int* in_sizes, int n_in,
                              void* d_out, int out_size, void* d_ws, size_t ws_size,
                              hipStream_t stream) {
    const float* nt_emb = (const float*)d_in[0];
    const char*  ei     = (const char*)d_in[1];
    const float* lm     = (const float*)d_in[2];
    const float* W1     = (const float*)d_in[3];
    const float* b1     = (const float*)d_in[4];
    const float* W2     = (const float*)d_in[5];
    const float* b2     = (const float*)d_in[6];
    float* out = (float*)d_out;

    long long E = (long long)in_sizes[1] / 2;   // edge_index is [2, E]
    int N = in_sizes[2];                        // lm_mask is [N]

    size_t needBytes = (size_t)N * 16 + 6144 + 64;
    if (ws_size >= needBytes) {
        unsigned short* T = (unsigned short*)d_ws;
        build_table<<<dim3((N + 255) / 256), dim3(256), 0, stream>>>(
            nt_emb, lm, W1, b1, W2, b2, T, N);
        unsigned nGroups = (unsigned)((E + 63) >> 6);
        unsigned blocks = (nGroups + 3u) >> 2;   // 4 waves per block, 1 group per wave
        lg_table_kernel<<<dim3(blocks), dim3(256), 0, stream>>>(ei, T, out, E, N);
    } else {
        lg_kernel<<<dim3(2048), dim3(256), 0, stream>>>(nt_emb, ei, lm, W1, b1, W2, b2, out, E);
    }
}